// Round 1
// baseline (4795.124 us; speedup 1.0000x reference)
//
#include <hip/hip_runtime.h>
#include <hip/hip_bf16.h>

#define NB 512
#define TT 512
#define HIDN 128
#define NWG 32
#define BPW 16
#define NTHREADS 512

typedef __bf16 bf16x8 __attribute__((ext_vector_type(8)));
typedef float f32x4 __attribute__((ext_vector_type(4)));
typedef unsigned int uint4v __attribute__((ext_vector_type(4)));

#define MFMA(a, b, c) __builtin_amdgcn_mfma_f32_16x16x32_bf16((a), (b), (c), 0, 0, 0)

__device__ __forceinline__ unsigned short f2bf(float f) {
  unsigned int u = __float_as_uint(f);
  u = u + 0x7FFFu + ((u >> 16) & 1u);
  return (unsigned short)(u >> 16);
}
__device__ __forceinline__ float bf2f(unsigned short s) {
  return __uint_as_float(((unsigned int)s) << 16);
}
__device__ __forceinline__ float sigm(float x) {
  return __builtin_amdgcn_rcpf(1.f + __builtin_amdgcn_exp2f(-1.44269504f * x));
}
__device__ __forceinline__ float tanh_(float x) {
  return 1.f - 2.f * __builtin_amdgcn_rcpf(1.f + __builtin_amdgcn_exp2f(2.88539008f * x));
}
__device__ __forceinline__ float softplus_(float x) {
  if (x > 15.f) return x;
  float e = __builtin_amdgcn_exp2f(1.44269504f * x);
  return 0.69314718f * __builtin_amdgcn_logf(1.f + e);
}

// Pack a [512][K] f32 weight matrix into bf16 fragment order:
// dst[((tau*ktiles + c)*64 + l)*8 + i] = W[tau*16 + (l&15)][c*32 + 8*(l>>4) + i]
__global__ void pack_w_kern(const float* __restrict__ src, unsigned short* __restrict__ dst,
                            int K, int ktiles) {
  int tid = blockIdx.x * 256 + threadIdx.x;
  int total = 32 * ktiles * 64;
  if (tid >= total) return;
  int l = tid & 63;
  int c = (tid >> 6) % ktiles;
  int tau = tid / (64 * ktiles);
  int n = tau * 16 + (l & 15);
  int k0 = c * 32 + 8 * (l >> 4);
  unsigned short o[8];
#pragma unroll
  for (int i = 0; i < 8; ++i) {
    int k = k0 + i;
    float v = (k < K) ? src[n * K + k] : 0.f;
    o[i] = f2bf(v);
  }
  *(uint4v*)(dst + (size_t)tid * 8) = *(const uint4v*)o;
}

// Build x0 (concat of cont feats + embeddings), bf16, A-fragment order, K padded 22->32:
// dst[((t*NWG + wg)*64 + l)*8 + i] = x[wg*16 + (l&15)][t][8*(l>>4) + i]
__global__ void pack_x0_kern(const float* __restrict__ xc, const int* __restrict__ idxs,
                             const int* __restrict__ idxi, const float* __restrict__ es,
                             const float* __restrict__ ei, unsigned short* __restrict__ dst) {
  int tid = blockIdx.x * 256 + threadIdx.x;
  if (tid >= TT * NWG * 64) return;
  int l = tid & 63;
  int wg = (tid >> 6) & 31;
  int t = tid >> 11;
  int bi = wg * BPW + (l & 15);
  int k0 = 8 * (l >> 4);
  int si = idxs[bi * TT + t];
  int it = idxi[bi * TT + t];
  const float* xr = xc + ((size_t)bi * TT + t) * 12;
  unsigned short o[8];
#pragma unroll
  for (int i = 0; i < 8; ++i) {
    int k = k0 + i;
    float v;
    if (k < 12)      v = xr[k];
    else if (k < 17) v = es[si * 5 + (k - 12)];
    else if (k < 22) v = ei[it * 5 + (k - 17)];
    else             v = 0.f;
    o[i] = f2bf(v);
  }
  *(uint4v*)(dst + (size_t)tid * 8) = *(const uint4v*)o;
}

__global__ __launch_bounds__(NTHREADS, 2) void lstm_fused_kern(
    const unsigned short* __restrict__ wp_ih0, const unsigned short* __restrict__ wp_hh0,
    const unsigned short* __restrict__ wp_ih1, const unsigned short* __restrict__ wp_hh1,
    const unsigned short* __restrict__ wp_ih2, const unsigned short* __restrict__ wp_hh2,
    const unsigned short* __restrict__ x0p,
    const float* __restrict__ b0, const float* __restrict__ b1, const float* __restrict__ b2,
    const float* __restrict__ Wm, const float* __restrict__ bm,
    const float* __restrict__ Wa, const float* __restrict__ ba,
    const float* __restrict__ v, float* __restrict__ out) {
  __shared__ unsigned short whh1s[65536];       // Whh1 frags, 131072 B
  __shared__ unsigned short h0s[16 * 136];      // h buffers, padded rows (272 B stride)
  __shared__ unsigned short h1s[16 * 136];
  __shared__ unsigned short h2s[16 * 136];
  __shared__ float wmS[128], waS[128];
  __shared__ float vS[16];

  const int tid = threadIdx.x;
  const int l = tid & 63;
  const int w = tid >> 6;  // wave 0..7, owns j in [w*16, w*16+16)
  const int wg = blockIdx.x;

  // stage Whh1 into LDS (frag-packed, conflict-free reads later)
  {
    const uint4v* s = (const uint4v*)wp_hh1;
    uint4v* d = (uint4v*)whh1s;
    for (int i = tid; i < 8192; i += NTHREADS) d[i] = s[i];
  }
  for (int i = tid; i < 16 * 136; i += NTHREADS) { h0s[i] = 0; h1s[i] = 0; h2s[i] = 0; }
  if (tid < 128) { wmS[tid] = Wm[tid]; waS[tid] = Wa[tid]; }
  if (tid < 16) vS[tid] = v[wg * BPW + tid];

  // Whh0 resident in registers: this wave's 4 gate-tiles x 4 k-tiles
  bf16x8 whh0r[4][4];
#pragma unroll
  for (int g = 0; g < 4; ++g)
#pragma unroll
    for (int c = 0; c < 4; ++c)
      whh0r[g][c] = *(const bf16x8*)(wp_hh0 + ((size_t)((g * 8 + w) * 4 + c) * 64 + l) * 8);

  const int j = w * 16 + (l & 15);
  float bia[3][4];
#pragma unroll
  for (int g = 0; g < 4; ++g) {
    bia[0][g] = b0[g * 128 + j];
    bia[1][g] = b1[g * 128 + j];
    bia[2][g] = b2[g * 128 + j];
  }
  float c0[4] = {0, 0, 0, 0}, c1[4] = {0, 0, 0, 0}, c2[4] = {0, 0, 0, 0};
  const float bmv = bm[0], bav = ba[0];
  const int row0 = (l >> 4) * 4;
  const int fragoff = (l & 15) * 136 + 8 * (l >> 4);  // + c*32 per k-tile

  __syncthreads();

  for (int t = 0; t < TT; ++t) {
    // ---------------- layer 0 ----------------
    bf16x8 ax = *(const bf16x8*)(x0p + (((size_t)t * NWG + wg) * 64 + l) * 8);
    bf16x8 ah[4];
#pragma unroll
    for (int c = 0; c < 4; ++c) ah[c] = *(const bf16x8*)(h0s + fragoff + c * 32);
    f32x4 acc[4];
#pragma unroll
    for (int g = 0; g < 4; ++g) { float b = bia[0][g]; f32x4 z = {b, b, b, b}; acc[g] = z; }
#pragma unroll
    for (int g = 0; g < 4; ++g) {
      bf16x8 bx = *(const bf16x8*)(wp_ih0 + ((size_t)(g * 8 + w) * 64 + l) * 8);
      acc[g] = MFMA(ax, bx, acc[g]);
    }
#pragma unroll
    for (int c = 0; c < 4; ++c)
#pragma unroll
      for (int g = 0; g < 4; ++g) acc[g] = MFMA(ah[c], whh0r[g][c], acc[g]);
    __syncthreads();  // all reads of old h0 done
#pragma unroll
    for (int r = 0; r < 4; ++r) {
      float ig = sigm(acc[0][r]);
      float fg = sigm(acc[1][r]);
      float gg = tanh_(acc[2][r]);
      float og = sigm(acc[3][r]);
      c0[r] = fg * c0[r] + ig * gg;
      float h = og * tanh_(c0[r]);
      h0s[(row0 + r) * 136 + j] = f2bf(h);
    }
    __syncthreads();  // new h0 visible

    // ---------------- layer 1 ----------------
    bf16x8 aX[4], aH[4];
#pragma unroll
    for (int c = 0; c < 4; ++c) {
      aX[c] = *(const bf16x8*)(h0s + fragoff + c * 32);
      aH[c] = *(const bf16x8*)(h1s + fragoff + c * 32);
    }
#pragma unroll
    for (int g = 0; g < 4; ++g) { float b = bia[1][g]; f32x4 z = {b, b, b, b}; acc[g] = z; }
#pragma unroll
    for (int c = 0; c < 4; ++c)
#pragma unroll
      for (int g = 0; g < 4; ++g) {
        bf16x8 bw = *(const bf16x8*)(wp_ih1 + ((size_t)((g * 8 + w) * 4 + c) * 64 + l) * 8);
        acc[g] = MFMA(aX[c], bw, acc[g]);
      }
#pragma unroll
    for (int c = 0; c < 4; ++c)
#pragma unroll
      for (int g = 0; g < 4; ++g) {
        bf16x8 bw = *(const bf16x8*)(whh1s + (((g * 8 + w) * 4 + c) * 64 + l) * 8);
        acc[g] = MFMA(aH[c], bw, acc[g]);
      }
    __syncthreads();
#pragma unroll
    for (int r = 0; r < 4; ++r) {
      float ig = sigm(acc[0][r]);
      float fg = sigm(acc[1][r]);
      float gg = tanh_(acc[2][r]);
      float og = sigm(acc[3][r]);
      c1[r] = fg * c1[r] + ig * gg;
      float h = og * tanh_(c1[r]);
      h1s[(row0 + r) * 136 + j] = f2bf(h);
    }
    __syncthreads();

    // ---------------- layer 2 ----------------
#pragma unroll
    for (int c = 0; c < 4; ++c) {
      aX[c] = *(const bf16x8*)(h1s + fragoff + c * 32);
      aH[c] = *(const bf16x8*)(h2s + fragoff + c * 32);
    }
#pragma unroll
    for (int g = 0; g < 4; ++g) { float b = bia[2][g]; f32x4 z = {b, b, b, b}; acc[g] = z; }
#pragma unroll
    for (int c = 0; c < 4; ++c)
#pragma unroll
      for (int g = 0; g < 4; ++g) {
        bf16x8 bw = *(const bf16x8*)(wp_ih2 + ((size_t)((g * 8 + w) * 4 + c) * 64 + l) * 8);
        acc[g] = MFMA(aX[c], bw, acc[g]);
      }
#pragma unroll
    for (int c = 0; c < 4; ++c)
#pragma unroll
      for (int g = 0; g < 4; ++g) {
        bf16x8 bw = *(const bf16x8*)(wp_hh2 + ((size_t)((g * 8 + w) * 4 + c) * 64 + l) * 8);
        acc[g] = MFMA(aH[c], bw, acc[g]);
      }
    __syncthreads();
#pragma unroll
    for (int r = 0; r < 4; ++r) {
      float ig = sigm(acc[0][r]);
      float fg = sigm(acc[1][r]);
      float gg = tanh_(acc[2][r]);
      float og = sigm(acc[3][r]);
      c2[r] = fg * c2[r] + ig * gg;
      float h = og * tanh_(c2[r]);
      h2s[(row0 + r) * 136 + j] = f2bf(h);
    }
    __syncthreads();  // h2 ready for head

    // ---------------- head ----------------
    if (tid < 256) {
      int s_ = tid & 7;
      int hd = (tid >> 3) & 1;
      int bi = tid >> 4;
      const float* wv = hd ? waS : wmS;
      const unsigned short* hrow = h2s + bi * 136 + s_ * 16;
      float part = 0.f;
#pragma unroll
      for (int kk = 0; kk < 16; ++kk) part += bf2f(hrow[kk]) * wv[s_ * 16 + kk];
      part += __shfl_xor(part, 1);
      part += __shfl_xor(part, 2);
      part += __shfl_xor(part, 4);
      if (s_ == 0) {
        float val = part + (hd ? bav : bmv);
        if (hd) val = softplus_(val);
        out[(((size_t)(wg * BPW + bi)) * TT + t) * 2 + hd] = val * vS[bi];
      }
    }
    // no barrier needed here: next write to h2s is >=5 barriers away
  }
}

extern "C" void kernel_launch(void* const* d_in, const int* in_sizes, int n_in,
                              void* d_out, int out_size, void* d_ws, size_t ws_size,
                              hipStream_t stream) {
  const float* x_cont    = (const float*)d_in[0];
  const int*   idx_shops = (const int*)d_in[1];
  const int*   idx_items = (const int*)d_in[2];
  const float* v         = (const float*)d_in[3];
  const float* emb_shops = (const float*)d_in[4];
  const float* emb_items = (const float*)d_in[5];
  const float* Wih0 = (const float*)d_in[6];
  const float* Whh0 = (const float*)d_in[7];
  const float* b0   = (const float*)d_in[8];
  const float* Wih1 = (const float*)d_in[9];
  const float* Whh1 = (const float*)d_in[10];
  const float* b1   = (const float*)d_in[11];
  const float* Wih2 = (const float*)d_in[12];
  const float* Whh2 = (const float*)d_in[13];
  const float* b2   = (const float*)d_in[14];
  const float* Wm   = (const float*)d_in[15];
  const float* bm   = (const float*)d_in[16];
  const float* Wa   = (const float*)d_in[17];
  const float* ba   = (const float*)d_in[18];
  float* out = (float*)d_out;

  unsigned short* ws = (unsigned short*)d_ws;
  unsigned short* wp_ih0 = ws;                  // 32*1*64*8   = 16384 el
  unsigned short* wp_hh0 = wp_ih0 + 16384;      // 32*4*64*8   = 65536 el
  unsigned short* wp_ih1 = wp_hh0 + 65536;
  unsigned short* wp_hh1 = wp_ih1 + 65536;
  unsigned short* wp_ih2 = wp_hh1 + 65536;
  unsigned short* wp_hh2 = wp_ih2 + 65536;
  unsigned short* x0p    = wp_hh2 + 65536;      // 512*32*64*8 = 8388608 el

  pack_w_kern<<<8, 256, 0, stream>>>(Wih0, wp_ih0, 22, 1);
  pack_w_kern<<<32, 256, 0, stream>>>(Whh0, wp_hh0, 128, 4);
  pack_w_kern<<<32, 256, 0, stream>>>(Wih1, wp_ih1, 128, 4);
  pack_w_kern<<<32, 256, 0, stream>>>(Whh1, wp_hh1, 128, 4);
  pack_w_kern<<<32, 256, 0, stream>>>(Wih2, wp_ih2, 128, 4);
  pack_w_kern<<<32, 256, 0, stream>>>(Whh2, wp_hh2, 128, 4);
  pack_x0_kern<<<4096, 256, 0, stream>>>(x_cont, idx_shops, idx_items,
                                         emb_shops, emb_items, x0p);
  lstm_fused_kern<<<NWG, NTHREADS, 0, stream>>>(wp_ih0, wp_hh0, wp_ih1, wp_hh1, wp_ih2, wp_hh2,
                                                x0p, b0, b1, b2, Wm, bm, Wa, ba, v, out);
}

// Round 2
// 2820.955 us; speedup vs baseline: 1.6998x; 1.6998x over previous
//
#include <hip/hip_runtime.h>
#include <hip/hip_bf16.h>

#define NB 512
#define TT 512
#define NWG 32
#define BPW 16
#define NTHREADS 512

typedef __bf16 bf16x8 __attribute__((ext_vector_type(8)));
typedef float f32x4 __attribute__((ext_vector_type(4)));
typedef unsigned int uint4v __attribute__((ext_vector_type(4)));

#define MFMA(a, b, c) __builtin_amdgcn_mfma_f32_16x16x32_bf16((a), (b), (c), 0, 0, 0)
// Raw barrier: LDS-producer drain only; global loads stay in flight (no vmcnt drain).
#define BAR() asm volatile("s_waitcnt lgkmcnt(0)\n\ts_barrier" ::: "memory")

__device__ __forceinline__ unsigned short f2bf(float f) {
  unsigned int u = __float_as_uint(f);
  u = u + 0x7FFFu + ((u >> 16) & 1u);
  return (unsigned short)(u >> 16);
}
__device__ __forceinline__ float bf2f(unsigned short s) {
  return __uint_as_float(((unsigned int)s) << 16);
}
__device__ __forceinline__ float sigm(float x) {
  return __builtin_amdgcn_rcpf(1.f + __builtin_amdgcn_exp2f(-1.44269504f * x));
}
__device__ __forceinline__ float tanh_(float x) {
  return 1.f - 2.f * __builtin_amdgcn_rcpf(1.f + __builtin_amdgcn_exp2f(2.88539008f * x));
}
__device__ __forceinline__ float softplus_(float x) {
  if (x > 15.f) return x;
  float e = __builtin_amdgcn_exp2f(1.44269504f * x);
  return 0.69314718f * __builtin_amdgcn_logf(1.f + e);
}

// Pack a [512][K] f32 weight matrix into bf16 fragment order:
// dst[((tau*ktiles + c)*64 + l)*8 + i] = W[tau*16 + (l&15)][c*32 + 8*(l>>4) + i]
__global__ void pack_w_kern(const float* __restrict__ src, unsigned short* __restrict__ dst,
                            int K, int ktiles) {
  int tid = blockIdx.x * 256 + threadIdx.x;
  int total = 32 * ktiles * 64;
  if (tid >= total) return;
  int l = tid & 63;
  int c = (tid >> 6) % ktiles;
  int tau = tid / (64 * ktiles);
  int n = tau * 16 + (l & 15);
  int k0 = c * 32 + 8 * (l >> 4);
  unsigned short o[8];
#pragma unroll
  for (int i = 0; i < 8; ++i) {
    int k = k0 + i;
    float v = (k < K) ? src[n * K + k] : 0.f;
    o[i] = f2bf(v);
  }
  *(uint4v*)(dst + (size_t)tid * 8) = *(const uint4v*)o;
}

// Build x0 (concat cont feats + embeddings), bf16, A-fragment order, K padded 22->32.
__global__ void pack_x0_kern(const float* __restrict__ xc, const int* __restrict__ idxs,
                             const int* __restrict__ idxi, const float* __restrict__ es,
                             const float* __restrict__ ei, unsigned short* __restrict__ dst) {
  int tid = blockIdx.x * 256 + threadIdx.x;
  if (tid >= TT * NWG * 64) return;
  int l = tid & 63;
  int wg = (tid >> 6) & 31;
  int t = tid >> 11;
  int bi = wg * BPW + (l & 15);
  int k0 = 8 * (l >> 4);
  int si = idxs[bi * TT + t];
  int it = idxi[bi * TT + t];
  const float* xr = xc + ((size_t)bi * TT + t) * 12;
  unsigned short o[8];
#pragma unroll
  for (int i = 0; i < 8; ++i) {
    int k = k0 + i;
    float v;
    if (k < 12)      v = xr[k];
    else if (k < 17) v = es[si * 5 + (k - 12)];
    else if (k < 22) v = ei[it * 5 + (k - 17)];
    else             v = 0.f;
    o[i] = f2bf(v);
  }
  *(uint4v*)(dst + (size_t)tid * 8) = *(const uint4v*)o;
}

__device__ __forceinline__ bf16x8 ldfrag(size_t base, int tau, int c, int l) {
  return *(const bf16x8*)((const unsigned short*)base +
                          (((size_t)(tau * 4 + c) * 64 + l) * 8));
}

__global__ __launch_bounds__(NTHREADS, 2) void lstm_fused_kern(
    const unsigned short* __restrict__ wp_ih0, const unsigned short* __restrict__ wp_hh0,
    const unsigned short* __restrict__ wp_ih1, const unsigned short* __restrict__ wp_hh1,
    const unsigned short* __restrict__ wp_ih2, const unsigned short* __restrict__ wp_hh2,
    const unsigned short* __restrict__ x0p,
    const float* __restrict__ b0, const float* __restrict__ b1, const float* __restrict__ b2,
    const float* __restrict__ Wm, const float* __restrict__ bm,
    const float* __restrict__ Wa, const float* __restrict__ ba,
    const float* __restrict__ v, float* __restrict__ out) {
  __shared__ unsigned short whh1s[65536];        // Whh1 frags, 131072 B (LDS-resident)
  __shared__ unsigned short h0s[2][16 * 136];    // parity double-buffered h state
  __shared__ unsigned short h1s[2][16 * 136];
  __shared__ unsigned short h2s[2][16 * 136];
  __shared__ float wmS[128], waS[128];
  __shared__ float vS[16];

  const int tid = threadIdx.x;
  const int l = tid & 63;
  const int w = tid >> 6;  // wave 0..7, owns j in [w*16, w*16+16)
  const int wg = blockIdx.x;

  {
    const uint4v* s = (const uint4v*)wp_hh1;
    uint4v* d = (uint4v*)whh1s;
    for (int i = tid; i < 8192; i += NTHREADS) d[i] = s[i];
  }
  for (int i = tid; i < 16 * 136; i += NTHREADS) { h0s[0][i] = 0; h1s[0][i] = 0; h2s[0][i] = 0; }
  if (tid < 128) { wmS[tid] = Wm[tid]; waS[tid] = Wa[tid]; }
  if (tid < 16) vS[tid] = v[wg * BPW + tid];

  // ih0 resident in registers (K-tile count 1): 4 frags
  bf16x8 ih0f[4];
#pragma unroll
  for (int g = 0; g < 4; ++g)
    ih0f[g] = *(const bf16x8*)(wp_ih0 + ((size_t)(g * 8 + w) * 64 + l) * 8);

  const int j = w * 16 + (l & 15);
  float bia[3][4];
#pragma unroll
  for (int g = 0; g < 4; ++g) {
    bia[0][g] = b0[g * 128 + j];
    bia[1][g] = b1[g * 128 + j];
    bia[2][g] = b2[g * 128 + j];
  }
  float c0[4] = {0, 0, 0, 0}, c1[4] = {0, 0, 0, 0}, c2[4] = {0, 0, 0, 0};
  const float bmv = bm[0], bav = ba[0];
  const int row0 = (l >> 4) * 4;
  const int fragoff = (l & 15) * 136 + 8 * (l >> 4);  // + c*32 per k-tile

  // Laundered stream base pointers (defeats LICM of loop-invariant weight loads)
  size_t p_hh0 = (size_t)wp_hh0, p_ih1 = (size_t)wp_ih1;
  size_t p_ih2 = (size_t)wp_ih2, p_hh2 = (size_t)wp_hh2;

  __syncthreads();

  // Prologue stream issues: hh0(t=0), ih1(t=0), ax(t=0)
  bf16x8 hh0f[4][4], ih1f[4][4], ih2f[4][4], hh2f[4][4];
#pragma unroll
  for (int g = 0; g < 4; ++g)
#pragma unroll
    for (int c = 0; c < 4; ++c) {
      hh0f[g][c] = ldfrag(p_hh0, g * 8 + w, c, l);
      ih1f[g][c] = ldfrag(p_ih1, g * 8 + w, c, l);
    }
  bf16x8 ax = *(const bf16x8*)(x0p + (((size_t)0 * NWG + wg) * 64 + l) * 8);

  for (int t = 0; t < TT; ++t) {
    asm volatile("" : "+s"(p_hh0), "+s"(p_ih1), "+s"(p_ih2), "+s"(p_hh2));
    const int rp = t & 1, wpp = rp ^ 1;

    // ---------------- layer 0 ----------------
    bf16x8 ah[4];
#pragma unroll
    for (int c = 0; c < 4; ++c) ah[c] = *(const bf16x8*)(&h0s[rp][0] + fragoff + c * 32);
    f32x4 accX[4], accH[4];
#pragma unroll
    for (int g = 0; g < 4; ++g) {
      float b = bia[0][g];
      f32x4 z = {b, b, b, b};
      accX[g] = MFMA(ax, ih0f[g], z);
      f32x4 zz = {0.f, 0.f, 0.f, 0.f};
      accH[g] = zz;
    }
#pragma unroll
    for (int c = 0; c < 4; ++c)
#pragma unroll
      for (int g = 0; g < 4; ++g) accH[g] = MFMA(ah[c], hh0f[g][c], accH[g]);
#pragma unroll
    for (int r = 0; r < 4; ++r) {
      float gi = accX[0][r] + accH[0][r];
      float gf = accX[1][r] + accH[1][r];
      float gg = accX[2][r] + accH[2][r];
      float go = accX[3][r] + accH[3][r];
      float ig = sigm(gi), fg = sigm(gf), gt = tanh_(gg), og = sigm(go);
      c0[r] = fg * c0[r] + ig * gt;
      h0s[wpp][(row0 + r) * 136 + j] = f2bf(og * tanh_(c0[r]));
    }
    // issue ih2 for this step (consumed in layer 2, ~2 phases away)
#pragma unroll
    for (int g = 0; g < 4; ++g)
#pragma unroll
      for (int c = 0; c < 4; ++c) ih2f[g][c] = ldfrag(p_ih2, g * 8 + w, c, l);
    BAR();

    // ---------------- layer 1 ----------------
    bf16x8 aX[4], aH[4];
#pragma unroll
    for (int c = 0; c < 4; ++c) {
      aX[c] = *(const bf16x8*)(&h0s[wpp][0] + fragoff + c * 32);
      aH[c] = *(const bf16x8*)(&h1s[rp][0] + fragoff + c * 32);
    }
#pragma unroll
    for (int g = 0; g < 4; ++g) {
      float b = bia[1][g];
      f32x4 z = {b, b, b, b};
      accX[g] = z;
      f32x4 zz = {0.f, 0.f, 0.f, 0.f};
      accH[g] = zz;
    }
#pragma unroll
    for (int c = 0; c < 4; ++c)
#pragma unroll
      for (int g = 0; g < 4; ++g) accX[g] = MFMA(aX[c], ih1f[g][c], accX[g]);
    // issue hh2 mid-layer-1 (ih1 regs dying, hh2 arriving)
#pragma unroll
    for (int g = 0; g < 4; ++g)
#pragma unroll
      for (int c = 0; c < 4; ++c) hh2f[g][c] = ldfrag(p_hh2, g * 8 + w, c, l);
#pragma unroll
    for (int c = 0; c < 4; ++c)
#pragma unroll
      for (int g = 0; g < 4; ++g) {
        bf16x8 bw = *(const bf16x8*)(whh1s + (((g * 8 + w) * 4 + c) * 64 + l) * 8);
        accH[g] = MFMA(aH[c], bw, accH[g]);
      }
#pragma unroll
    for (int r = 0; r < 4; ++r) {
      float gi = accX[0][r] + accH[0][r];
      float gf = accX[1][r] + accH[1][r];
      float gg = accX[2][r] + accH[2][r];
      float go = accX[3][r] + accH[3][r];
      float ig = sigm(gi), fg = sigm(gf), gt = tanh_(gg), og = sigm(go);
      c1[r] = fg * c1[r] + ig * gt;
      h1s[wpp][(row0 + r) * 136 + j] = f2bf(og * tanh_(c1[r]));
    }
    BAR();

    // ---------------- layer 2 ----------------
#pragma unroll
    for (int c = 0; c < 4; ++c) {
      aX[c] = *(const bf16x8*)(&h1s[wpp][0] + fragoff + c * 32);
      aH[c] = *(const bf16x8*)(&h2s[rp][0] + fragoff + c * 32);
    }
#pragma unroll
    for (int g = 0; g < 4; ++g) {
      float b = bia[2][g];
      f32x4 z = {b, b, b, b};
      accX[g] = z;
      f32x4 zz = {0.f, 0.f, 0.f, 0.f};
      accH[g] = zz;
    }
#pragma unroll
    for (int c = 0; c < 4; ++c)
#pragma unroll
      for (int g = 0; g < 4; ++g) {
        accX[g] = MFMA(aX[c], ih2f[g][c], accX[g]);
        accH[g] = MFMA(aH[c], hh2f[g][c], accH[g]);
      }
    // issue next-step streams: hh0(t+1), ih1(t+1), ax(t+1)
#pragma unroll
    for (int g = 0; g < 4; ++g)
#pragma unroll
      for (int c = 0; c < 4; ++c) {
        hh0f[g][c] = ldfrag(p_hh0, g * 8 + w, c, l);
        ih1f[g][c] = ldfrag(p_ih1, g * 8 + w, c, l);
      }
    {
      int t1 = (t + 1 < TT) ? t + 1 : t;
      ax = *(const bf16x8*)(x0p + (((size_t)t1 * NWG + wg) * 64 + l) * 8);
    }
#pragma unroll
    for (int r = 0; r < 4; ++r) {
      float gi = accX[0][r] + accH[0][r];
      float gf = accX[1][r] + accH[1][r];
      float gg = accX[2][r] + accH[2][r];
      float go = accX[3][r] + accH[3][r];
      float ig = sigm(gi), fg = sigm(gf), gt = tanh_(gg), og = sigm(go);
      c2[r] = fg * c2[r] + ig * gt;
      h2s[wpp][(row0 + r) * 136 + j] = f2bf(og * tanh_(c2[r]));
    }
    BAR();

    // ---------------- head (waves 0-3; no trailing barrier needed) ----------------
    if (tid < 256) {
      int s_ = tid & 7;
      int hd = (tid >> 3) & 1;
      int bi = tid >> 4;
      const float* wv = hd ? waS : wmS;
      const unsigned short* hrow = &h2s[wpp][0] + bi * 136 + s_ * 16;
      float part = 0.f;
#pragma unroll
      for (int kk = 0; kk < 16; ++kk) part += bf2f(hrow[kk]) * wv[s_ * 16 + kk];
      part += __shfl_xor(part, 1);
      part += __shfl_xor(part, 2);
      part += __shfl_xor(part, 4);
      if (s_ == 0) {
        float val = part + (hd ? bav : bmv);
        if (hd) val = softplus_(val);
        out[(((size_t)(wg * BPW + bi)) * TT + t) * 2 + hd] = val * vS[bi];
      }
    }
  }
}

extern "C" void kernel_launch(void* const* d_in, const int* in_sizes, int n_in,
                              void* d_out, int out_size, void* d_ws, size_t ws_size,
                              hipStream_t stream) {
  const float* x_cont    = (const float*)d_in[0];
  const int*   idx_shops = (const int*)d_in[1];
  const int*   idx_items = (const int*)d_in[2];
  const float* v         = (const float*)d_in[3];
  const float* emb_shops = (const float*)d_in[4];
  const float* emb_items = (const float*)d_in[5];
  const float* Wih0 = (const float*)d_in[6];
  const float* Whh0 = (const float*)d_in[7];
  const float* b0   = (const float*)d_in[8];
  const float* Wih1 = (const float*)d_in[9];
  const float* Whh1 = (const float*)d_in[10];
  const float* b1   = (const float*)d_in[11];
  const float* Wih2 = (const float*)d_in[12];
  const float* Whh2 = (const float*)d_in[13];
  const float* b2   = (const float*)d_in[14];
  const float* Wm   = (const float*)d_in[15];
  const float* bm   = (const float*)d_in[16];
  const float* Wa   = (const float*)d_in[17];
  const float* ba   = (const float*)d_in[18];
  float* out = (float*)d_out;

  unsigned short* ws = (unsigned short*)d_ws;
  unsigned short* wp_ih0 = ws;                  // 32*1*64*8   = 16384 el
  unsigned short* wp_hh0 = wp_ih0 + 16384;      // 32*4*64*8   = 65536 el
  unsigned short* wp_ih1 = wp_hh0 + 65536;
  unsigned short* wp_hh1 = wp_ih1 + 65536;
  unsigned short* wp_ih2 = wp_hh1 + 65536;
  unsigned short* wp_hh2 = wp_ih2 + 65536;
  unsigned short* x0p    = wp_hh2 + 65536;      // 512*32*64*8 = 8388608 el

  pack_w_kern<<<8, 256, 0, stream>>>(Wih0, wp_ih0, 22, 1);
  pack_w_kern<<<32, 256, 0, stream>>>(Whh0, wp_hh0, 128, 4);
  pack_w_kern<<<32, 256, 0, stream>>>(Wih1, wp_ih1, 128, 4);
  pack_w_kern<<<32, 256, 0, stream>>>(Whh1, wp_hh1, 128, 4);
  pack_w_kern<<<32, 256, 0, stream>>>(Wih2, wp_ih2, 128, 4);
  pack_w_kern<<<32, 256, 0, stream>>>(Whh2, wp_hh2, 128, 4);
  pack_x0_kern<<<4096, 256, 0, stream>>>(x_cont, idx_shops, idx_items,
                                         emb_shops, emb_items, x0p);
  lstm_fused_kern<<<NWG, NTHREADS, 0, stream>>>(wp_ih0, wp_hh0, wp_ih1, wp_hh1, wp_ih2, wp_hh2,
                                                x0p, b0, b1, b2, Wm, bm, Wa, ba, v, out);
}

// Round 5
// 1595.229 us; speedup vs baseline: 3.0059x; 1.7684x over previous
//
#include <hip/hip_runtime.h>
#include <hip/hip_bf16.h>

#define TT 512
#define NTILE 32
#define BPW 16
#define NTHREADS 512
#define CH 32          // steps per chunk
#define NCH 16         // chunks (512/32)

typedef __bf16 bf16x8 __attribute__((ext_vector_type(8)));
typedef float f32x4 __attribute__((ext_vector_type(4)));
typedef unsigned int uint4v __attribute__((ext_vector_type(4)));

#define MFMA(a, b, c) __builtin_amdgcn_mfma_f32_16x16x32_bf16((a), (b), (c), 0, 0, 0)
// Raw barrier: LDS drain only; global loads stay in flight.
#define BAR() asm volatile("s_waitcnt lgkmcnt(0)\n\ts_barrier" ::: "memory")

__device__ __forceinline__ unsigned short f2bf(float f) {
  unsigned int u = __float_as_uint(f);
  u = u + 0x7FFFu + ((u >> 16) & 1u);
  return (unsigned short)(u >> 16);
}
__device__ __forceinline__ float bf2f(unsigned short s) {
  return __uint_as_float(((unsigned int)s) << 16);
}
__device__ __forceinline__ float sigm(float x) {
  return __builtin_amdgcn_rcpf(1.f + __builtin_amdgcn_exp2f(-1.44269504f * x));
}
__device__ __forceinline__ float tanh_(float x) {
  return 1.f - 2.f * __builtin_amdgcn_rcpf(1.f + __builtin_amdgcn_exp2f(2.88539008f * x));
}
__device__ __forceinline__ float softplus_(float x) {
  if (x > 15.f) return x;
  float e = __builtin_amdgcn_exp2f(1.44269504f * x);
  return 0.69314718f * __builtin_amdgcn_logf(1.f + e);
}

// Pack a [512][K] f32 weight matrix into bf16 B-fragment order:
// dst[((tau*ktiles + c)*64 + l)*8 + i] = W[tau*16 + (l&15)][c*32 + 8*(l>>4) + i]
__global__ void pack_w_kern(const float* __restrict__ src, unsigned short* __restrict__ dst,
                            int K, int ktiles) {
  int tid = blockIdx.x * 256 + threadIdx.x;
  int total = 32 * ktiles * 64;
  if (tid >= total) return;
  int l = tid & 63;
  int c = (tid >> 6) % ktiles;
  int tau = tid / (64 * ktiles);
  int n = tau * 16 + (l & 15);
  int k0 = c * 32 + 8 * (l >> 4);
  unsigned short o[8];
#pragma unroll
  for (int i = 0; i < 8; ++i) {
    int k = k0 + i;
    float v = (k < K) ? src[n * K + k] : 0.f;
    o[i] = f2bf(v);
  }
  *(uint4v*)(dst + (size_t)tid * 8) = *(const uint4v*)o;
}

// Build x0 (concat cont feats + embeddings), bf16, A-fragment order, K padded 22->32.
__global__ void pack_x0_kern(const float* __restrict__ xc, const int* __restrict__ idxs,
                             const int* __restrict__ idxi, const float* __restrict__ es,
                             const float* __restrict__ ei, unsigned short* __restrict__ dst) {
  int tid = blockIdx.x * 256 + threadIdx.x;
  if (tid >= TT * NTILE * 64) return;
  int l = tid & 63;
  int b = (tid >> 6) & 31;
  int t = tid >> 11;
  int bi = b * BPW + (l & 15);
  int k0 = 8 * (l >> 4);
  int si = idxs[bi * TT + t];
  int it = idxi[bi * TT + t];
  const float* xr = xc + ((size_t)bi * TT + t) * 12;
  unsigned short o[8];
#pragma unroll
  for (int i = 0; i < 8; ++i) {
    int k = k0 + i;
    float v;
    if (k < 12)      v = xr[k];
    else if (k < 17) v = es[si * 5 + (k - 12)];
    else if (k < 22) v = ei[it * 5 + (k - 17)];
    else             v = 0.f;
    o[i] = f2bf(v);
  }
  *(uint4v*)(dst + (size_t)tid * 8) = *(const uint4v*)o;
}

// Gaussian head for step slot `tt` (reads h2 from buf slot tt). Waves 0-3 only.
__device__ __forceinline__ void head_step(
    int b, int t, const unsigned short* slotbase,
    const float* wmS, const float* waS, const float* vS,
    float bmv, float bav, float* out) {
  const int tid = threadIdx.x;
  if (tid >= 256) return;
  int s_ = tid & 7, hd = (tid >> 3) & 1, bi = tid >> 4;
  const float* wv = hd ? waS : wmS;
  const unsigned short* hrow = slotbase + bi * 136 + s_ * 16;
  float part = 0.f;
#pragma unroll
  for (int kk = 0; kk < 16; ++kk) part += bf2f(hrow[kk]) * wv[s_ * 16 + kk];
  part += __shfl_xor(part, 1);
  part += __shfl_xor(part, 2);
  part += __shfl_xor(part, 4);
  if (s_ == 0) {
    float val = part + (hd ? bav : bmv);
    if (hd) val = softplus_(val);
    out[(((size_t)(b * BPW + bi)) * TT + t) * 2 + hd] = val * vS[bi];
  }
}

// One layer's scan over one chunk of CH steps. Weights register-resident for the
// whole chunk. In-place LDS chunk buffer: slot tt holds this layer's input until
// step tt, then this layer's output h(tt). One raw barrier per step; the
// one-step-ahead inF prefetch guarantees all reads of slot tt precede (via each
// wave's own lgkmcnt(0) at the step-top barrier) the step-tt write.
template<int L>
__device__ __forceinline__ void scan_chunk(
    int k, int b, const unsigned short* wp_ih, const unsigned short* wp_hh,
    const unsigned short* x0p, unsigned short* buf, unsigned short* carry,
    float (&cc)[4], const float (&bia)[4],
    const float* wmS, const float* waS, const float* vS,
    float bmv, float bav, float* out) {
  const int tid = threadIdx.x;
  const int l = tid & 63;
  const int w = tid >> 6;
  const int j = w * 16 + (l & 15);
  const int row0 = (l >> 4) * 4;
  const int fragoff = (l & 15) * 136 + 8 * (l >> 4);  // + c*32 per k-tile

  // -------- weight burst: whole layer into registers (held for all CH steps) ----
  bf16x8 ihf[4][4], hhf[4][4];
  if (L == 0) {
#pragma unroll
    for (int g = 0; g < 4; ++g)
      ihf[g][0] = *(const bf16x8*)(wp_ih + ((size_t)(g * 8 + w) * 64 + l) * 8);
  } else {
#pragma unroll
    for (int g = 0; g < 4; ++g)
#pragma unroll
      for (int c = 0; c < 4; ++c)
        ihf[g][c] = *(const bf16x8*)(wp_ih + ((size_t)((g * 8 + w) * 4 + c) * 64 + l) * 8);
  }
#pragma unroll
  for (int g = 0; g < 4; ++g)
#pragma unroll
    for (int c = 0; c < 4; ++c)
      hhf[g][c] = *(const bf16x8*)(wp_hh + ((size_t)((g * 8 + w) * 4 + c) * 64 + l) * 8);

  // -------- input fragments for step 0 (prefetch discipline starts here) --------
  bf16x8 inF[4], inFn[4];
  if (L == 0) {
    inF[0] = *(const bf16x8*)(x0p + (((size_t)(k * CH) * NTILE + b) * 64 + l) * 8);
    inFn[0] = inF[0];
  } else {
#pragma unroll
    for (int c = 0; c < 4; ++c) {
      inF[c] = *(const bf16x8*)(buf + fragoff + c * 32);
      inFn[c] = inF[c];
    }
  }

  for (int tt = 0; tt < CH; ++tt) {
    const int t = k * CH + tt;
    BAR();  // h(tt-1) writes visible; all reads of slot tt already drained
    if (L == 2) {
      if (tt > 0)
        head_step(b, t - 1, buf + (tt - 1) * 2176, wmS, waS, vS, bmv, bav, out);
    }
    const unsigned short* ahb = (tt == 0) ? carry : buf + (tt - 1) * 2176;
    bf16x8 ah[4];
#pragma unroll
    for (int c = 0; c < 4; ++c) ah[c] = *(const bf16x8*)(ahb + fragoff + c * 32);
    // prefetch next step's input (slot tt+1 — not written until step tt+1)
    if (tt < CH - 1) {
      if (L == 0) {
        inFn[0] = *(const bf16x8*)(x0p + (((size_t)(t + 1) * NTILE + b) * 64 + l) * 8);
      } else {
#pragma unroll
        for (int c = 0; c < 4; ++c)
          inFn[c] = *(const bf16x8*)(buf + (tt + 1) * 2176 + fragoff + c * 32);
      }
    }
    f32x4 acc[4];
#pragma unroll
    for (int g = 0; g < 4; ++g) { float bb = bia[g]; f32x4 z = {bb, bb, bb, bb}; acc[g] = z; }
    if (L == 0) {
#pragma unroll
      for (int g = 0; g < 4; ++g) acc[g] = MFMA(inF[0], ihf[g][0], acc[g]);
    } else {
#pragma unroll
      for (int c = 0; c < 4; ++c)
#pragma unroll
        for (int g = 0; g < 4; ++g) acc[g] = MFMA(inF[c], ihf[g][c], acc[g]);
    }
#pragma unroll
    for (int c = 0; c < 4; ++c)
#pragma unroll
      for (int g = 0; g < 4; ++g) acc[g] = MFMA(ah[c], hhf[g][c], acc[g]);
#pragma unroll
    for (int r = 0; r < 4; ++r) {
      float ig = sigm(acc[0][r]);
      float fg = sigm(acc[1][r]);
      float gt = tanh_(acc[2][r]);
      float og = sigm(acc[3][r]);
      cc[r] = fg * cc[r] + ig * gt;
      float h = og * tanh_(cc[r]);
      unsigned short hb = f2bf(h);
      buf[tt * 2176 + (row0 + r) * 136 + j] = hb;
      if (tt == CH - 1) carry[(row0 + r) * 136 + j] = hb;
    }
#pragma unroll
    for (int c = 0; c < 4; ++c) inF[c] = inFn[c];
  }
  if (L == 2) {
    BAR();  // make h2(CH-1) visible for the final head
    head_step(b, k * CH + CH - 1, buf + (CH - 1) * 2176, wmS, waS, vS, bmv, bav, out);
  }
}

__global__ __launch_bounds__(NTHREADS, 2) void lstm_seq_kern(
    const unsigned short* __restrict__ wp_ih0, const unsigned short* __restrict__ wp_hh0,
    const unsigned short* __restrict__ wp_ih1, const unsigned short* __restrict__ wp_hh1,
    const unsigned short* __restrict__ wp_ih2, const unsigned short* __restrict__ wp_hh2,
    const unsigned short* __restrict__ x0p,
    const float* __restrict__ b0, const float* __restrict__ b1, const float* __restrict__ b2,
    const float* __restrict__ Wm, const float* __restrict__ bm,
    const float* __restrict__ Wa, const float* __restrict__ ba,
    const float* __restrict__ v, float* __restrict__ out) {
  __shared__ unsigned short bufS[CH * 2176];    // in-place h-chunk buffer (139 KB)
  __shared__ unsigned short carryS[3 * 2176];   // per-layer h carry (13 KB)
  __shared__ float wmS[128], waS[128], vS[16];

  const int tid = threadIdx.x;
  const int b = blockIdx.x;
  const int l = tid & 63;
  const int w = tid >> 6;
  const int j = w * 16 + (l & 15);

  for (int i = tid; i < 3 * 2176; i += NTHREADS) carryS[i] = 0;
  if (tid < 128) { wmS[tid] = Wm[tid]; waS[tid] = Wa[tid]; }
  if (tid < 16) vS[tid] = v[b * BPW + tid];

  float bia0[4], bia1[4], bia2[4];
#pragma unroll
  for (int g = 0; g < 4; ++g) {
    bia0[g] = b0[g * 128 + j];
    bia1[g] = b1[g * 128 + j];
    bia2[g] = b2[g * 128 + j];
  }
  float cc0[4] = {0, 0, 0, 0}, cc1[4] = {0, 0, 0, 0}, cc2[4] = {0, 0, 0, 0};
  const float bmv = bm[0], bav = ba[0];

  // Laundered weight base pointers: block LICM from hoisting bursts out of the
  // chunk loop (3 layers of weights can't all be register-resident at once).
  size_t p_ih0 = (size_t)wp_ih0, p_hh0 = (size_t)wp_hh0;
  size_t p_ih1 = (size_t)wp_ih1, p_hh1 = (size_t)wp_hh1;
  size_t p_ih2 = (size_t)wp_ih2, p_hh2 = (size_t)wp_hh2;

  __syncthreads();

  for (int k = 0; k < NCH; ++k) {
    asm volatile("" : "+s"(p_ih0), "+s"(p_hh0), "+s"(p_ih1), "+s"(p_hh1),
                      "+s"(p_ih2), "+s"(p_hh2));
    scan_chunk<0>(k, b, (const unsigned short*)p_ih0, (const unsigned short*)p_hh0,
                  x0p, bufS, carryS, cc0, bia0, wmS, waS, vS, bmv, bav, out);
    scan_chunk<1>(k, b, (const unsigned short*)p_ih1, (const unsigned short*)p_hh1,
                  x0p, bufS, carryS + 2176, cc1, bia1, wmS, waS, vS, bmv, bav, out);
    scan_chunk<2>(k, b, (const unsigned short*)p_ih2, (const unsigned short*)p_hh2,
                  x0p, bufS, carryS + 4352, cc2, bia2, wmS, waS, vS, bmv, bav, out);
  }
}

extern "C" void kernel_launch(void* const* d_in, const int* in_sizes, int n_in,
                              void* d_out, int out_size, void* d_ws, size_t ws_size,
                              hipStream_t stream) {
  const float* x_cont    = (const float*)d_in[0];
  const int*   idx_shops = (const int*)d_in[1];
  const int*   idx_items = (const int*)d_in[2];
  const float* v         = (const float*)d_in[3];
  const float* emb_shops = (const float*)d_in[4];
  const float* emb_items = (const float*)d_in[5];
  const float* Wih0 = (const float*)d_in[6];
  const float* Whh0 = (const float*)d_in[7];
  const float* b0   = (const float*)d_in[8];
  const float* Wih1 = (const float*)d_in[9];
  const float* Whh1 = (const float*)d_in[10];
  const float* b1   = (const float*)d_in[11];
  const float* Wih2 = (const float*)d_in[12];
  const float* Whh2 = (const float*)d_in[13];
  const float* b2   = (const float*)d_in[14];
  const float* Wm   = (const float*)d_in[15];
  const float* bm   = (const float*)d_in[16];
  const float* Wa   = (const float*)d_in[17];
  const float* ba   = (const float*)d_in[18];
  float* out = (float*)d_out;

  unsigned short* ws = (unsigned short*)d_ws;
  unsigned short* wp_ih0 = ws;                  // 32*1*64*8   = 16384 el
  unsigned short* wp_hh0 = wp_ih0 + 16384;      // 32*4*64*8   = 65536 el
  unsigned short* wp_ih1 = wp_hh0 + 65536;
  unsigned short* wp_hh1 = wp_ih1 + 65536;
  unsigned short* wp_ih2 = wp_hh1 + 65536;
  unsigned short* wp_hh2 = wp_ih2 + 65536;
  unsigned short* x0p    = wp_hh2 + 65536;      // 512*32*64*8 = 8388608 el (total 17.5 MB)

  pack_w_kern<<<8, 256, 0, stream>>>(Wih0, wp_ih0, 22, 1);
  pack_w_kern<<<32, 256, 0, stream>>>(Whh0, wp_hh0, 128, 4);
  pack_w_kern<<<32, 256, 0, stream>>>(Wih1, wp_ih1, 128, 4);
  pack_w_kern<<<32, 256, 0, stream>>>(Whh1, wp_hh1, 128, 4);
  pack_w_kern<<<32, 256, 0, stream>>>(Wih2, wp_ih2, 128, 4);
  pack_w_kern<<<32, 256, 0, stream>>>(Whh2, wp_hh2, 128, 4);
  pack_x0_kern<<<4096, 256, 0, stream>>>(x_cont, idx_shops, idx_items,
                                         emb_shops, emb_items, x0p);
  lstm_seq_kern<<<NTILE, NTHREADS, 0, stream>>>(wp_ih0, wp_hh0, wp_ih1, wp_hh1,
                                                wp_ih2, wp_hh2, x0p,
                                                b0, b1, b2, Wm, bm, Wa, ba, v, out);
}